// Round 4
// baseline (6109.846 us; speedup 1.0000x reference)
//
#include <hip/hip_runtime.h>
#include <math.h>

// Problem constants (fixed by the reference setup_inputs)
#define BATCH 32
#define CH    192
#define TFEAT 2048
#define TTXT  512
#define NEGINF (-1e9f)

#define ATTN_ELEMS ((size_t)BATCH * TFEAT * TTXT)   // 33,554,432
#define DUR_OFF    ATTN_ELEMS
#define NEG_OFF    (ATTN_ELEMS + (size_t)BATCH * TTXT)

__device__ __forceinline__ void gload_lds16(const float* g, float* l) {
  __builtin_amdgcn_global_load_lds(
      (const __attribute__((address_space(1))) void*)g,
      (__attribute__((address_space(3))) void*)l, 16, 0, 0);
}

// ---------------------------------------------------------------------------
// Kernel P: W1[b,c,s] = m*exp(-2*logs), W2[b,c,s] = -0.5*exp(-2*logs)
// Written into the attn region of d_out (fully rewritten later by k_attn).
// ---------------------------------------------------------------------------
__global__ void k_prep(const float* __restrict__ m_p,
                       const float* __restrict__ logs_p,
                       float* __restrict__ w1, float* __restrict__ w2) {
  int gid = blockIdx.x * 256 + threadIdx.x;    // 0 .. 3,145,727
  float m = m_p[gid];
  float l = logs_p[gid];
  float r = __expf(-2.0f * l);
  w1[gid] = m * r;
  w2[gid] = -0.5f * r;
}

// ---------------------------------------------------------------------------
// Kernel A: cadd[b][s] = sum_c(-0.5*log(2pi) - logs) + sum_c(-0.5*m^2*r)
// ---------------------------------------------------------------------------
__global__ void k_cadd(const float* __restrict__ m_p,
                       const float* __restrict__ logs_p,
                       float* __restrict__ cadd) {
  int gid = blockIdx.x * 256 + threadIdx.x;        // 0 .. 16383
  int b = gid >> 9, s = gid & (TTXT - 1);
  const float* mp = m_p    + (size_t)b * CH * TTXT + s;
  const float* lp = logs_p + (size_t)b * CH * TTXT + s;
  float acc = -0.5f * 1.8378770664093453f * (float)CH;   // -C/2 * log(2*pi)
  #pragma unroll 4
  for (int c = 0; c < CH; ++c) {
    float l = lp[(size_t)c * TTXT];
    float m = mp[(size_t)c * TTXT];
    float r = __expf(-2.0f * l);
    acc -= l + 0.5f * m * m * r;
  }
  cadd[gid] = acc;
}

// ---------------------------------------------------------------------------
// Kernel B: neg[b,t,s] = sum_c z*(W1 + z*W2) + cadd[b,s]
// fp32 vector GEMM. 512 threads, per-thread acc[4][8] = 32 regs (live set
// ~70 regs << 128: scratch spill structurally impossible — the R1-R3
// 2.9 GB phantom WRITE traffic was acc[8][8] spill at the 128-reg budget).
// Chunked XCD swizzle: 256 consecutive work-blocks per XCD -> z-panel (sb
// siblings adjacent) and W-panel (tb siblings at stride 4, reuse dist
// ~1.2 MB < 4 MB L2) reuse inside each XCD's private L2.
// ---------------------------------------------------------------------------
#define BM 128
#define BN 128
#define BK 16

__global__ __launch_bounds__(512, 4)
void k_gemm(const float* __restrict__ z_p,
            const float* __restrict__ w1g, const float* __restrict__ w2g,
            const float* __restrict__ cadd, float* __restrict__ neg) {
  __shared__ float Az[BK][BM];
  __shared__ float B1[BK][BN];
  __shared__ float B2[BK][BN];

  // chunked XCD swizzle (2048 blocks, 8 XCDs, 256 per chunk; bijective)
  int blk = (blockIdx.x & 7) * 256 + (blockIdx.x >> 3);
  int sb = blk & 3;            // TTXT/BN = 4
  int tb = (blk >> 2) & 15;    // TFEAT/BM = 16
  int b  = blk >> 6;
  int tid = threadIdx.x;
  int tx = tid & 15;           // col group (8 cols: tx*4, 64+tx*4)
  int ty = tid >> 4;           // 0..31, 4 rows each
  int wid  = tid >> 6;         // wave 0..7
  int lane = tid & 63;
  int lr = lane >> 5;          // row-within-pair
  int lc = (lane & 31) * 4;    // col (float4 granularity)

  const float* zb  = z_p + (size_t)b * CH * TFEAT + (size_t)tb * BM;
  const float* w1b = w1g + (size_t)b * CH * TTXT  + (size_t)sb * BN;
  const float* w2b = w2g + (size_t)b * CH * TTXT  + (size_t)sb * BN;

  float acc[4][8];
  #pragma unroll
  for (int i = 0; i < 4; ++i)
    #pragma unroll
    for (int j = 0; j < 8; ++j) acc[i][j] = 0.0f;

  for (int ko = 0; ko < CH / BK; ++ko) {
    int k0 = ko * BK;
    // stage 3 tiles: wave wid covers rows {2*wid, 2*wid+1} of each tile
    int kr = k0 + 2 * wid + lr;          // per-lane global k-row
    int kd = 2 * wid;                    // wave-uniform LDS row base
    gload_lds16(zb  + (size_t)kr * TFEAT + lc, &Az[kd][0]);
    gload_lds16(w1b + (size_t)kr * TTXT  + lc, &B1[kd][0]);
    gload_lds16(w2b + (size_t)kr * TTXT  + lc, &B2[kd][0]);
    __syncthreads();                     // drains vmcnt (loads landed)

    #pragma unroll
    for (int kk = 0; kk < BK; ++kk) {
      float4 av = *(const float4*)&Az[kk][ty * 4];
      float4 p0 = *(const float4*)&B1[kk][tx * 4];
      float4 p1 = *(const float4*)&B1[kk][64 + tx * 4];
      float4 q0 = *(const float4*)&B2[kk][tx * 4];
      float4 q1 = *(const float4*)&B2[kk][64 + tx * 4];
      float a[4]   = {av.x, av.y, av.z, av.w};
      float w1v[8] = {p0.x, p0.y, p0.z, p0.w, p1.x, p1.y, p1.z, p1.w};
      float w2v[8] = {q0.x, q0.y, q0.z, q0.w, q1.x, q1.y, q1.z, q1.w};
      #pragma unroll
      for (int i = 0; i < 4; ++i)
        #pragma unroll
        for (int j = 0; j < 8; ++j)
          acc[i][j] = fmaf(a[i], fmaf(a[i], w2v[j], w1v[j]), acc[i][j]);
    }
    __syncthreads();                     // tile consumed before restage
  }

  // epilogue: + cadd, store. rows tb*128 + ty*4 + i; cols tx*4 / 64+tx*4
  const float* cb = cadd + b * TTXT + sb * BN;
  float c0[4], c1[4];
  #pragma unroll
  for (int j = 0; j < 4; ++j) { c0[j] = cb[tx * 4 + j]; c1[j] = cb[64 + tx * 4 + j]; }
  float* ob = neg + (size_t)b * TFEAT * TTXT + (size_t)(tb * BM + ty * 4) * TTXT + sb * BN;
  #pragma unroll
  for (int i = 0; i < 4; ++i) {
    float4 o0 = {acc[i][0] + c0[0], acc[i][1] + c0[1], acc[i][2] + c0[2], acc[i][3] + c0[3]};
    float4 o1 = {acc[i][4] + c1[0], acc[i][5] + c1[1], acc[i][6] + c1[2], acc[i][7] + c1[3]};
    float* row = ob + (size_t)i * TTXT;
    *(float4*)(row + tx * 4)      = o0;
    *(float4*)(row + 64 + tx * 4) = o1;
  }
}

// ---------------------------------------------------------------------------
// Kernel C: forward DP with LDS ring-3 staging (global_load_lds + counted
// vmcnt, 2 chunks ahead) + decision bits in LDS + windowed backtrack.
// One wave per batch element, x = 8*lane + j.
// ---------------------------------------------------------------------------
#define CHUNK 4                       // rows per staged chunk
#define NCH   (TFEAT / CHUNK)         // 512 chunks

#define VMCNT(n) asm volatile("s_waitcnt vmcnt(" #n ")" ::: "memory")

template<bool MASKED>
__device__ __forceinline__ void dp_rows4(float (&prev)[8], const float (*R)[TTXT],
                                         int y0, int xbase, int lane,
                                         unsigned (*bits)[64]) {
  unsigned packed = 0;
  #pragma unroll
  for (int r = 0; r < 4; ++r) {
    int y = y0 + r;
    float4 u = *(const float4*)&R[r][lane * 8];
    float4 v = *(const float4*)&R[r][lane * 8 + 4];
    float nf[8] = {u.x, u.y, u.z, u.w, v.x, v.y, v.z, v.w};
    float up = __shfl_up(prev[7], 1);
    // decision bits (prev = values[y-1]): bit = (x!=0)&((x==y)|(prev[x]<prev[x-1]))
    unsigned byte;
    {
      unsigned bit = (prev[0] < up) ? 1u : 0u;
      if (MASKED && xbase == y) bit = 1u;
      if (lane == 0) bit = 0u;
      byte = bit;
    }
    #pragma unroll
    for (int j = 1; j < 8; ++j) {
      unsigned bit = (prev[j] < prev[j - 1]) ? 1u : 0u;
      if (MASKED && (xbase + j) == y) bit = 1u;
      byte |= bit << j;
    }
    // value update
    float vleft0;
    if (MASKED) vleft0 = (lane == 0) ? ((y == 0) ? 0.0f : NEGINF) : up;
    else        vleft0 = (lane == 0) ? NEGINF : up;
    float nv[8];
    {
      float vc = (MASKED && xbase == y) ? NEGINF : prev[0];
      nv[0] = fmaxf(vc, vleft0) + nf[0];
    }
    #pragma unroll
    for (int j = 1; j < 8; ++j) {
      float vc = (MASKED && (xbase + j) == y) ? NEGINF : prev[j];
      nv[j] = fmaxf(vc, prev[j - 1]) + nf[j];
    }
    #pragma unroll
    for (int j = 0; j < 8; ++j) prev[j] = nv[j];
    packed |= byte << (r * 8);
  }
  bits[y0 >> 2][lane] = packed;
}

__global__ __launch_bounds__(64, 1)
void k_dp(const float* __restrict__ neg, float* __restrict__ dur,
          int* __restrict__ idx_out, const float* __restrict__ x_mask) {
  __shared__ unsigned bits[TFEAT / 4][64];       // 131072 B
  __shared__ float ring[3][CHUNK][TTXT];         //  24576 B (total 152 KiB)
  int b = blockIdx.x;
  int lane = threadIdx.x;
  const float* nb = neg + (size_t)b * TFEAT * TTXT;
  int xbase = lane * 8;

  float prev[8];
  #pragma unroll
  for (int j = 0; j < 8; ++j) prev[j] = NEGINF;

  // stage chunk c (rows 4c..4c+3) into ring[c%3]: 8 x 1KB global_load_lds
  auto stage = [&](int c) {
    int m = c % 3;
    const float* src = nb + (size_t)c * CHUNK * TTXT + lane * 4;
    #pragma unroll
    for (int r = 0; r < CHUNK; ++r) {
      gload_lds16(src + (size_t)r * TTXT,       &ring[m][r][0]);
      gload_lds16(src + (size_t)r * TTXT + 256, &ring[m][r][256]);
    }
  };

  stage(0);
  stage(1);                                      // 16 outstanding
  for (int c = 0; c < NCH; ++c) {
    if (c + 2 < NCH)      { stage(c + 2); VMCNT(16); }  // c landed; c+1,c+2 in flight
    else if (c + 2 == NCH) VMCNT(8);
    else                   VMCNT(0);
    const float (*R)[TTXT] = ring[c % 3];
    if (c < TTXT / CHUNK) dp_rows4<true >(prev, R, c * CHUNK, xbase, lane, bits);
    else                  dp_rows4<false>(prev, R, c * CHUNK, xbase, lane, bits);
  }
  __syncthreads();

  // ---- windowed backtrack: per yq (4 rows), hold words (xq0, xq0-1) in regs,
  // speculatively prefetch 3 words of the next yq (idx moves <= 4 per window).
  const float* xm = x_mask + (size_t)b * TTXT;
  int idx = TTXT - 1, cnt = 0;
  int xq0 = (TTXT - 1) >> 3;
  unsigned c0 = bits[TFEAT / 4 - 1][xq0];
  unsigned c1 = bits[TFEAT / 4 - 1][xq0 - 1];
  for (int yq = TFEAT / 4 - 1; yq >= 0; --yq) {
    unsigned n0 = 0, n1 = 0, n2 = 0;
    if (yq > 0) {
      int i1 = xq0 - 1 > 0 ? xq0 - 1 : 0;
      int i2 = xq0 - 2 > 0 ? xq0 - 2 : 0;
      n0 = bits[yq - 1][xq0];
      n1 = bits[yq - 1][i1];
      n2 = bits[yq - 1][i2];
    }
    #pragma unroll
    for (int r = 3; r >= 0; --r) {
      int y = yq * 4 + r;
      if (lane == 0) idx_out[b * TFEAT + y] = idx;
      cnt++;
      unsigned w = ((idx >> 3) == xq0) ? c0 : c1;
      unsigned bit = (w >> (r * 8 + (idx & 7))) & 1u;
      if (bit) {
        if (lane == 0) dur[b * TTXT + idx] = (float)cnt * xm[idx];
        cnt = 0;
        idx--;
      }
    }
    int nxq = idx >> 3;
    c0 = (nxq == xq0) ? n0 : n1;
    c1 = (nxq == xq0) ? n1 : n2;
    xq0 = nxq;
  }
  if (lane == 0) dur[b * TTXT] = (float)cnt * xm[0];   // idx == 0 tail run
}

// ---------------------------------------------------------------------------
// Kernel D: attn[b,y,x] = (x == idx[y]) * x_mask[b,x] * y_mask[b,y]
// ---------------------------------------------------------------------------
__global__ void k_attn(const int* __restrict__ idx_arr,
                       const float* __restrict__ x_mask,
                       const float* __restrict__ y_mask,
                       float* __restrict__ attn) {
  size_t gid = (size_t)blockIdx.x * 256 + threadIdx.x;
  size_t e = gid << 2;               // 4 floats per thread
  int b = (int)(e >> 20);            // TFEAT*TTXT = 2^20
  int rem = (int)(e & 1048575u);
  int y = rem >> 9;
  int x0 = rem & 511;
  int idx = idx_arr[b * TFEAT + y];
  float4 v = {0.f, 0.f, 0.f, 0.f};
  int d = idx - x0;
  if (d >= 0 && d < 4) {
    ((float*)&v)[d] = x_mask[b * TTXT + idx] * y_mask[b * TFEAT + y];
  }
  *(float4*)(attn + e) = v;
}

// ---------------------------------------------------------------------------
extern "C" void kernel_launch(void* const* d_in, const int* in_sizes, int n_in,
                              void* d_out, int out_size, void* d_ws, size_t ws_size,
                              hipStream_t stream) {
  const float* z_p    = (const float*)d_in[0];
  const float* m_p    = (const float*)d_in[1];
  const float* logs_p = (const float*)d_in[2];
  const float* x_mask = (const float*)d_in[3];
  const float* y_mask = (const float*)d_in[4];

  float* out  = (float*)d_out;
  float* attn = out;
  float* dur  = out + DUR_OFF;
  float* neg  = out + NEG_OFF;

  // W1/W2 scratch lives in the attn region (fully rewritten by k_attn later)
  float* w1s = attn;
  float* w2s = attn + (size_t)BATCH * CH * TTXT;      // 3,145,728 floats each

  // workspace: cadd (64 KiB) + idx array (256 KiB)
  float* cadd = (float*)d_ws;
  int*   idxa = (int*)((char*)d_ws + 65536);

  k_prep<<<(BATCH * CH * TTXT) / 256, 256, 0, stream>>>(m_p, logs_p, w1s, w2s);
  k_cadd<<<(BATCH * TTXT) / 256, 256, 0, stream>>>(m_p, logs_p, cadd);
  k_gemm<<<BATCH * (TFEAT / BM) * (TTXT / BN), 512, 0, stream>>>(z_p, w1s, w2s, cadd, neg);
  k_dp<<<BATCH, 64, 0, stream>>>(neg, dur, idxa, x_mask);
  k_attn<<<(int)(ATTN_ELEMS / 4 / 256), 256, 0, stream>>>(idxa, x_mask, y_mask, attn);
}

// Round 5
// 2148.473 us; speedup vs baseline: 2.8438x; 2.8438x over previous
//
#include <hip/hip_runtime.h>
#include <math.h>

// Problem constants (fixed by the reference setup_inputs)
#define BATCH 32
#define CH    192
#define TFEAT 2048
#define TTXT  512
#define NEGINF (-1e9f)

#define ATTN_ELEMS ((size_t)BATCH * TFEAT * TTXT)   // 33,554,432
#define DUR_OFF    ATTN_ELEMS
#define NEG_OFF    (ATTN_ELEMS + (size_t)BATCH * TTXT)

__device__ __forceinline__ void gload_lds16(const float* g, float* l) {
  __builtin_amdgcn_global_load_lds(
      (const __attribute__((address_space(1))) void*)g,
      (__attribute__((address_space(3))) void*)l, 16, 0, 0);
}

// ---------------------------------------------------------------------------
// Kernel P: W1[b,c,s] = m*exp(-2*logs), W2[b,c,s] = -0.5*exp(-2*logs)
// Written into the attn region of d_out (fully rewritten later by k_attn).
// ---------------------------------------------------------------------------
__global__ void k_prep(const float* __restrict__ m_p,
                       const float* __restrict__ logs_p,
                       float* __restrict__ w1, float* __restrict__ w2) {
  int gid = blockIdx.x * 256 + threadIdx.x;    // 0 .. 3,145,727
  float m = m_p[gid];
  float l = logs_p[gid];
  float r = __expf(-2.0f * l);
  w1[gid] = m * r;
  w2[gid] = -0.5f * r;
}

// ---------------------------------------------------------------------------
// Kernel A: cadd[b][s] = sum_c(-0.5*log(2pi) - logs) + sum_c(-0.5*m^2*r)
// ---------------------------------------------------------------------------
__global__ void k_cadd(const float* __restrict__ m_p,
                       const float* __restrict__ logs_p,
                       float* __restrict__ cadd) {
  int gid = blockIdx.x * 256 + threadIdx.x;        // 0 .. 16383
  int b = gid >> 9, s = gid & (TTXT - 1);
  const float* mp = m_p    + (size_t)b * CH * TTXT + s;
  const float* lp = logs_p + (size_t)b * CH * TTXT + s;
  float acc = -0.5f * 1.8378770664093453f * (float)CH;   // -C/2 * log(2*pi)
  #pragma unroll 4
  for (int c = 0; c < CH; ++c) {
    float l = lp[(size_t)c * TTXT];
    float m = mp[(size_t)c * TTXT];
    float r = __expf(-2.0f * l);
    acc -= l + 0.5f * m * m * r;
  }
  cadd[gid] = acc;
}

// ---------------------------------------------------------------------------
// Kernel B: neg[b,t,s] = sum_c z*(W1 + z*W2) + cadd[b,s]
// fp32 vector GEMM, 512 threads, acc[4][8].
// SPILL HISTORY: hipcc's occupancy heuristic allocates at the occupancy step
// BELOW the launch-bounds budget and spills the difference:
//   R1-R3: launch_bounds(256,2) (budget 256) -> alloc 128, spill, 4.4 GB traffic
//   R4:    launch_bounds(512,4) (budget 128) -> alloc  64, spill, 22  GB traffic
// Fix: amdgpu_waves_per_eu(4,4) pins the target to exactly 4 waves/EU ->
// 128-reg budget the allocator may actually use (live set ~60). Inner loop
// additionally split into two 4-col halves so concurrent fragments <= 12 regs.
// ---------------------------------------------------------------------------
#define BM 128
#define BN 128
#define BK 16

__global__ __launch_bounds__(512)
__attribute__((amdgpu_waves_per_eu(4, 4)))
void k_gemm(const float* __restrict__ z_p,
            const float* __restrict__ w1g, const float* __restrict__ w2g,
            const float* __restrict__ cadd, float* __restrict__ neg) {
  __shared__ float Az[BK][BM];
  __shared__ float B1[BK][BN];
  __shared__ float B2[BK][BN];

  // chunked XCD swizzle (2048 blocks, 8 XCDs, 256 per chunk; bijective)
  int blk = (blockIdx.x & 7) * 256 + (blockIdx.x >> 3);
  int sb = blk & 3;            // TTXT/BN = 4
  int tb = (blk >> 2) & 15;    // TFEAT/BM = 16
  int b  = blk >> 6;
  int tid = threadIdx.x;
  int tx = tid & 15;           // col group (8 cols: tx*4, 64+tx*4)
  int ty = tid >> 4;           // 0..31, 4 rows each
  int wid  = tid >> 6;         // wave 0..7
  int lane = tid & 63;
  int lr = lane >> 5;          // row-within-pair
  int lc = (lane & 31) * 4;    // col (float4 granularity)

  const float* zb  = z_p + (size_t)b * CH * TFEAT + (size_t)tb * BM;
  const float* w1b = w1g + (size_t)b * CH * TTXT  + (size_t)sb * BN;
  const float* w2b = w2g + (size_t)b * CH * TTXT  + (size_t)sb * BN;

  float acc[4][8];
  #pragma unroll
  for (int i = 0; i < 4; ++i)
    #pragma unroll
    for (int j = 0; j < 8; ++j) acc[i][j] = 0.0f;

  for (int ko = 0; ko < CH / BK; ++ko) {
    int k0 = ko * BK;
    // stage 3 tiles: wave wid covers rows {2*wid, 2*wid+1} of each tile
    int kr = k0 + 2 * wid + lr;          // per-lane global k-row
    int kd = 2 * wid;                    // wave-uniform LDS row base
    gload_lds16(zb  + (size_t)kr * TFEAT + lc, &Az[kd][0]);
    gload_lds16(w1b + (size_t)kr * TTXT  + lc, &B1[kd][0]);
    gload_lds16(w2b + (size_t)kr * TTXT  + lc, &B2[kd][0]);
    __syncthreads();                     // drains vmcnt (loads landed)

    #pragma unroll
    for (int kk = 0; kk < BK; ++kk) {
      float4 av = *(const float4*)&Az[kk][ty * 4];
      float a[4] = {av.x, av.y, av.z, av.w};
      {  // half 0: cols tx*4 .. +3 -> acc[.][0..3]
        float4 p0 = *(const float4*)&B1[kk][tx * 4];
        float4 q0 = *(const float4*)&B2[kk][tx * 4];
        float w1v[4] = {p0.x, p0.y, p0.z, p0.w};
        float w2v[4] = {q0.x, q0.y, q0.z, q0.w};
        #pragma unroll
        for (int i = 0; i < 4; ++i)
          #pragma unroll
          for (int j = 0; j < 4; ++j)
            acc[i][j] = fmaf(a[i], fmaf(a[i], w2v[j], w1v[j]), acc[i][j]);
      }
      {  // half 1: cols 64+tx*4 .. +3 -> acc[.][4..7]
        float4 p1 = *(const float4*)&B1[kk][64 + tx * 4];
        float4 q1 = *(const float4*)&B2[kk][64 + tx * 4];
        float w1v[4] = {p1.x, p1.y, p1.z, p1.w};
        float w2v[4] = {q1.x, q1.y, q1.z, q1.w};
        #pragma unroll
        for (int i = 0; i < 4; ++i)
          #pragma unroll
          for (int j = 0; j < 4; ++j)
            acc[i][4 + j] = fmaf(a[i], fmaf(a[i], w2v[j], w1v[j]), acc[i][4 + j]);
      }
    }
    __syncthreads();                     // tile consumed before restage
  }

  // epilogue: + cadd, store. rows tb*128 + ty*4 + i; cols tx*4 / 64+tx*4
  const float* cb = cadd + b * TTXT + sb * BN;
  float c0[4], c1[4];
  #pragma unroll
  for (int j = 0; j < 4; ++j) { c0[j] = cb[tx * 4 + j]; c1[j] = cb[64 + tx * 4 + j]; }
  float* ob = neg + (size_t)b * TFEAT * TTXT + (size_t)(tb * BM + ty * 4) * TTXT + sb * BN;
  #pragma unroll
  for (int i = 0; i < 4; ++i) {
    float4 o0 = {acc[i][0] + c0[0], acc[i][1] + c0[1], acc[i][2] + c0[2], acc[i][3] + c0[3]};
    float4 o1 = {acc[i][4] + c1[0], acc[i][5] + c1[1], acc[i][6] + c1[2], acc[i][7] + c1[3]};
    float* row = ob + (size_t)i * TTXT;
    *(float4*)(row + tx * 4)      = o0;
    *(float4*)(row + 64 + tx * 4) = o1;
  }
}

// ---------------------------------------------------------------------------
// Kernel C: forward DP with LDS ring-3 staging (global_load_lds + counted
// vmcnt, 2 chunks ahead) + decision bits in LDS + windowed backtrack.
// One wave per batch element, x = 8*lane + j.
// ---------------------------------------------------------------------------
#define CHUNK 4                       // rows per staged chunk
#define NCH   (TFEAT / CHUNK)         // 512 chunks

#define VMCNT(n) asm volatile("s_waitcnt vmcnt(" #n ")" ::: "memory")

template<bool MASKED>
__device__ __forceinline__ void dp_rows4(float (&prev)[8], const float (*R)[TTXT],
                                         int y0, int xbase, int lane,
                                         unsigned (*bits)[64]) {
  unsigned packed = 0;
  #pragma unroll
  for (int r = 0; r < 4; ++r) {
    int y = y0 + r;
    float4 u = *(const float4*)&R[r][lane * 8];
    float4 v = *(const float4*)&R[r][lane * 8 + 4];
    float nf[8] = {u.x, u.y, u.z, u.w, v.x, v.y, v.z, v.w};
    float up = __shfl_up(prev[7], 1);
    // decision bits (prev = values[y-1]): bit = (x!=0)&((x==y)|(prev[x]<prev[x-1]))
    unsigned byte;
    {
      unsigned bit = (prev[0] < up) ? 1u : 0u;
      if (MASKED && xbase == y) bit = 1u;
      if (lane == 0) bit = 0u;
      byte = bit;
    }
    #pragma unroll
    for (int j = 1; j < 8; ++j) {
      unsigned bit = (prev[j] < prev[j - 1]) ? 1u : 0u;
      if (MASKED && (xbase + j) == y) bit = 1u;
      byte |= bit << j;
    }
    // value update
    float vleft0;
    if (MASKED) vleft0 = (lane == 0) ? ((y == 0) ? 0.0f : NEGINF) : up;
    else        vleft0 = (lane == 0) ? NEGINF : up;
    float nv[8];
    {
      float vc = (MASKED && xbase == y) ? NEGINF : prev[0];
      nv[0] = fmaxf(vc, vleft0) + nf[0];
    }
    #pragma unroll
    for (int j = 1; j < 8; ++j) {
      float vc = (MASKED && (xbase + j) == y) ? NEGINF : prev[j];
      nv[j] = fmaxf(vc, prev[j - 1]) + nf[j];
    }
    #pragma unroll
    for (int j = 0; j < 8; ++j) prev[j] = nv[j];
    packed |= byte << (r * 8);
  }
  bits[y0 >> 2][lane] = packed;
}

__global__ __launch_bounds__(64, 1)
void k_dp(const float* __restrict__ neg, float* __restrict__ dur,
          int* __restrict__ idx_out, const float* __restrict__ x_mask) {
  __shared__ unsigned bits[TFEAT / 4][64];       // 131072 B
  __shared__ float ring[3][CHUNK][TTXT];         //  24576 B (total 152 KiB)
  int b = blockIdx.x;
  int lane = threadIdx.x;
  const float* nb = neg + (size_t)b * TFEAT * TTXT;
  int xbase = lane * 8;

  float prev[8];
  #pragma unroll
  for (int j = 0; j < 8; ++j) prev[j] = NEGINF;

  // stage chunk c (rows 4c..4c+3) into ring[c%3]: 8 x 1KB global_load_lds
  auto stage = [&](int c) {
    int m = c % 3;
    const float* src = nb + (size_t)c * CHUNK * TTXT + lane * 4;
    #pragma unroll
    for (int r = 0; r < CHUNK; ++r) {
      gload_lds16(src + (size_t)r * TTXT,       &ring[m][r][0]);
      gload_lds16(src + (size_t)r * TTXT + 256, &ring[m][r][256]);
    }
  };

  stage(0);
  stage(1);                                      // 16 outstanding
  for (int c = 0; c < NCH; ++c) {
    if (c + 2 < NCH)      { stage(c + 2); VMCNT(16); }  // c landed; c+1,c+2 in flight
    else if (c + 2 == NCH) VMCNT(8);
    else                   VMCNT(0);
    const float (*R)[TTXT] = ring[c % 3];
    if (c < TTXT / CHUNK) dp_rows4<true >(prev, R, c * CHUNK, xbase, lane, bits);
    else                  dp_rows4<false>(prev, R, c * CHUNK, xbase, lane, bits);
  }
  __syncthreads();

  // ---- windowed backtrack: per yq (4 rows), hold words (xq0, xq0-1) in regs,
  // speculatively prefetch 3 words of the next yq (idx moves <= 4 per window).
  const float* xm = x_mask + (size_t)b * TTXT;
  int idx = TTXT - 1, cnt = 0;
  int xq0 = (TTXT - 1) >> 3;
  unsigned c0 = bits[TFEAT / 4 - 1][xq0];
  unsigned c1 = bits[TFEAT / 4 - 1][xq0 - 1];
  for (int yq = TFEAT / 4 - 1; yq >= 0; --yq) {
    unsigned n0 = 0, n1 = 0, n2 = 0;
    if (yq > 0) {
      int i1 = xq0 - 1 > 0 ? xq0 - 1 : 0;
      int i2 = xq0 - 2 > 0 ? xq0 - 2 : 0;
      n0 = bits[yq - 1][xq0];
      n1 = bits[yq - 1][i1];
      n2 = bits[yq - 1][i2];
    }
    #pragma unroll
    for (int r = 3; r >= 0; --r) {
      int y = yq * 4 + r;
      if (lane == 0) idx_out[b * TFEAT + y] = idx;
      cnt++;
      unsigned w = ((idx >> 3) == xq0) ? c0 : c1;
      unsigned bit = (w >> (r * 8 + (idx & 7))) & 1u;
      if (bit) {
        if (lane == 0) dur[b * TTXT + idx] = (float)cnt * xm[idx];
        cnt = 0;
        idx--;
      }
    }
    int nxq = idx >> 3;
    c0 = (nxq == xq0) ? n0 : n1;
    c1 = (nxq == xq0) ? n1 : n2;
    xq0 = nxq;
  }
  if (lane == 0) dur[b * TTXT] = (float)cnt * xm[0];   // idx == 0 tail run
}

// ---------------------------------------------------------------------------
// Kernel D: attn[b,y,x] = (x == idx[y]) * x_mask[b,x] * y_mask[b,y]
// ---------------------------------------------------------------------------
__global__ void k_attn(const int* __restrict__ idx_arr,
                       const float* __restrict__ x_mask,
                       const float* __restrict__ y_mask,
                       float* __restrict__ attn) {
  size_t gid = (size_t)blockIdx.x * 256 + threadIdx.x;
  size_t e = gid << 2;               // 4 floats per thread
  int b = (int)(e >> 20);            // TFEAT*TTXT = 2^20
  int rem = (int)(e & 1048575u);
  int y = rem >> 9;
  int x0 = rem & 511;
  int idx = idx_arr[b * TFEAT + y];
  float4 v = {0.f, 0.f, 0.f, 0.f};
  int d = idx - x0;
  if (d >= 0 && d < 4) {
    ((float*)&v)[d] = x_mask[b * TTXT + idx] * y_mask[b * TFEAT + y];
  }
  *(float4*)(attn + e) = v;
}

// ---------------------------------------------------------------------------
extern "C" void kernel_launch(void* const* d_in, const int* in_sizes, int n_in,
                              void* d_out, int out_size, void* d_ws, size_t ws_size,
                              hipStream_t stream) {
  const float* z_p    = (const float*)d_in[0];
  const float* m_p    = (const float*)d_in[1];
  const float* logs_p = (const float*)d_in[2];
  const float* x_mask = (const float*)d_in[3];
  const float* y_mask = (const float*)d_in[4];

  float* out  = (float*)d_out;
  float* attn = out;
  float* dur  = out + DUR_OFF;
  float* neg  = out + NEG_OFF;

  // W1/W2 scratch lives in the attn region (fully rewritten by k_attn later)
  float* w1s = attn;
  float* w2s = attn + (size_t)BATCH * CH * TTXT;      // 3,145,728 floats each

  // workspace: cadd (64 KiB) + idx array (256 KiB)
  float* cadd = (float*)d_ws;
  int*   idxa = (int*)((char*)d_ws + 65536);

  k_prep<<<(BATCH * CH * TTXT) / 256, 256, 0, stream>>>(m_p, logs_p, w1s, w2s);
  k_cadd<<<(BATCH * TTXT) / 256, 256, 0, stream>>>(m_p, logs_p, cadd);
  k_gemm<<<BATCH * (TFEAT / BM) * (TTXT / BN), 512, 0, stream>>>(z_p, w1s, w2s, cadd, neg);
  k_dp<<<BATCH, 64, 0, stream>>>(neg, dur, idxa, x_mask);
  k_attn<<<(int)(ATTN_ELEMS / 4 / 256), 256, 0, stream>>>(idxa, x_mask, y_mask, attn);
}

// Round 6
// 998.557 us; speedup vs baseline: 6.1187x; 2.1516x over previous
//
#include <hip/hip_runtime.h>
#include <math.h>

// Problem constants (fixed by the reference setup_inputs)
#define BATCH 32
#define CH    192
#define TFEAT 2048
#define TTXT  512
#define NEGINF (-1e9f)

#define ATTN_ELEMS ((size_t)BATCH * TFEAT * TTXT)   // 33,554,432
#define DUR_OFF    ATTN_ELEMS
#define NEG_OFF    (ATTN_ELEMS + (size_t)BATCH * TTXT)

__device__ __forceinline__ void gload_lds16(const float* g, float* l) {
  __builtin_amdgcn_global_load_lds(
      (const __attribute__((address_space(1))) void*)g,
      (__attribute__((address_space(3))) void*)l, 16, 0, 0);
}

// ---------------------------------------------------------------------------
// Kernel P: W1[b,c,s] = m*exp(-2*logs), W2[b,c,s] = -0.5*exp(-2*logs)
// Written into the attn region of d_out (fully rewritten later by k_attn).
// ---------------------------------------------------------------------------
__global__ void k_prep(const float* __restrict__ m_p,
                       const float* __restrict__ logs_p,
                       float* __restrict__ w1, float* __restrict__ w2) {
  int gid = blockIdx.x * 256 + threadIdx.x;    // 0 .. 3,145,727
  float m = m_p[gid];
  float l = logs_p[gid];
  float r = __expf(-2.0f * l);
  w1[gid] = m * r;
  w2[gid] = -0.5f * r;
}

// ---------------------------------------------------------------------------
// Kernel A: cadd[b][s] = sum_c(-0.5*log(2pi) - logs) + sum_c(-0.5*m^2*r)
// ---------------------------------------------------------------------------
__global__ void k_cadd(const float* __restrict__ m_p,
                       const float* __restrict__ logs_p,
                       float* __restrict__ cadd) {
  int gid = blockIdx.x * 256 + threadIdx.x;        // 0 .. 16383
  int b = gid >> 9, s = gid & (TTXT - 1);
  const float* mp = m_p    + (size_t)b * CH * TTXT + s;
  const float* lp = logs_p + (size_t)b * CH * TTXT + s;
  float acc = -0.5f * 1.8378770664093453f * (float)CH;   // -C/2 * log(2*pi)
  #pragma unroll 4
  for (int c = 0; c < CH; ++c) {
    float l = lp[(size_t)c * TTXT];
    float m = mp[(size_t)c * TTXT];
    float r = __expf(-2.0f * l);
    acc -= l + 0.5f * m * m * r;
  }
  cadd[gid] = acc;
}

// ---------------------------------------------------------------------------
// Kernel B: neg[b,t,s] = sum_c z*(W1 + z*W2) + cadd[b,s]
// fp32 vector GEMM, 512 threads, acc[8][4].
// SPILL HISTORY: hipcc pins this kernel's allocation at 64 VGPRs no matter
// what launch_bounds / waves_per_eu say (R4: 22 GB spill, R5: 6.6 GB spill).
// So the live set is DESIGNED for 64: acc[8][4]=32 + A-frag 8 + B-frags 8 +
// addressing ~12 = ~60. Per kk: 4 ds_read_b128 / 64 FMAs (LDS 48cy vs VALU
// 128cy -> VALU-bound). A-reads are wave-broadcast (free); B-reads 512B
// contiguous. sched_barrier(0) per kk stops cross-kk fragment pipelining.
// Per-output-element summation order identical to R1-R5 (ko asc, kk asc).
// ---------------------------------------------------------------------------
#define BM 128
#define BN 128
#define BK 16

__global__ __launch_bounds__(512)
void k_gemm(const float* __restrict__ z_p,
            const float* __restrict__ w1g, const float* __restrict__ w2g,
            const float* __restrict__ cadd, float* __restrict__ neg) {
  __shared__ float Az[BK][BM];
  __shared__ float B1[BK][BN];
  __shared__ float B2[BK][BN];

  // chunked XCD swizzle (2048 blocks, 8 XCDs, 256 per chunk; bijective)
  int blk = (blockIdx.x & 7) * 256 + (blockIdx.x >> 3);
  int sb = blk & 3;            // TTXT/BN = 4
  int tb = (blk >> 2) & 15;    // TFEAT/BM = 16
  int b  = blk >> 6;
  int tid = threadIdx.x;
  int tx = tid & 31;           // col group: 4 cols at tx*4
  int ty = tid >> 5;           // row group: 8 rows at ty*8  (0..15)
  int wid  = tid >> 6;         // wave 0..7
  int lane = tid & 63;
  int lr = lane >> 5;          // row-within-pair
  int lc = (lane & 31) * 4;    // col (float4 granularity)

  const float* zb  = z_p + (size_t)b * CH * TFEAT + (size_t)tb * BM;
  const float* w1b = w1g + (size_t)b * CH * TTXT  + (size_t)sb * BN;
  const float* w2b = w2g + (size_t)b * CH * TTXT  + (size_t)sb * BN;

  float acc[8][4];
  #pragma unroll
  for (int i = 0; i < 8; ++i)
    #pragma unroll
    for (int j = 0; j < 4; ++j) acc[i][j] = 0.0f;

  for (int ko = 0; ko < CH / BK; ++ko) {
    int k0 = ko * BK;
    // stage 3 tiles: wave wid covers rows {2*wid, 2*wid+1} of each tile
    int kr = k0 + 2 * wid + lr;          // per-lane global k-row
    int kd = 2 * wid;                    // wave-uniform LDS row base
    gload_lds16(zb  + (size_t)kr * TFEAT + lc, &Az[kd][0]);
    gload_lds16(w1b + (size_t)kr * TTXT  + lc, &B1[kd][0]);
    gload_lds16(w2b + (size_t)kr * TTXT  + lc, &B2[kd][0]);
    __syncthreads();                     // drains vmcnt (loads landed)

    #pragma unroll
    for (int kk = 0; kk < BK; ++kk) {
      float4 a0 = *(const float4*)&Az[kk][ty * 8];
      float4 a1 = *(const float4*)&Az[kk][ty * 8 + 4];
      float4 p  = *(const float4*)&B1[kk][tx * 4];
      float4 q  = *(const float4*)&B2[kk][tx * 4];
      float a[8]   = {a0.x, a0.y, a0.z, a0.w, a1.x, a1.y, a1.z, a1.w};
      float w1v[4] = {p.x, p.y, p.z, p.w};
      float w2v[4] = {q.x, q.y, q.z, q.w};
      #pragma unroll
      for (int i = 0; i < 8; ++i)
        #pragma unroll
        for (int j = 0; j < 4; ++j)
          acc[i][j] = fmaf(a[i], fmaf(a[i], w2v[j], w1v[j]), acc[i][j]);
      __builtin_amdgcn_sched_barrier(0); // keep live set <= 64 VGPRs
    }
    __syncthreads();                     // tile consumed before restage
  }

  // epilogue: + cadd, store. rows tb*128 + ty*8 + i; cols sb*128 + tx*4
  float4 cb4 = *(const float4*)(cadd + b * TTXT + sb * BN + tx * 4);
  float c0[4] = {cb4.x, cb4.y, cb4.z, cb4.w};
  float* ob = neg + (size_t)b * TFEAT * TTXT + (size_t)(tb * BM + ty * 8) * TTXT + sb * BN;
  #pragma unroll
  for (int i = 0; i < 8; ++i) {
    float4 o = {acc[i][0] + c0[0], acc[i][1] + c0[1], acc[i][2] + c0[2], acc[i][3] + c0[3]};
    *(float4*)(ob + (size_t)i * TTXT + tx * 4) = o;
  }
}

// ---------------------------------------------------------------------------
// Kernel C: forward DP with LDS ring-4 staging (global_load_lds + counted
// vmcnt, 3 chunks ahead = 24KB in flight, covers ~1200cy) + decision bits in
// LDS + windowed backtrack. One wave per batch element, x = 8*lane + j.
// LDS: bits 128KiB + ring 32KiB = 160KiB exact.
// ---------------------------------------------------------------------------
#define CHUNK 4                       // rows per staged chunk
#define NCH   (TFEAT / CHUNK)         // 512 chunks

#define VMCNT(n) asm volatile("s_waitcnt vmcnt(" #n ")" ::: "memory")

template<bool MASKED>
__device__ __forceinline__ void dp_rows4(float (&prev)[8], const float (*R)[TTXT],
                                         int y0, int xbase, int lane,
                                         unsigned (*bits)[64]) {
  unsigned packed = 0;
  #pragma unroll
  for (int r = 0; r < 4; ++r) {
    int y = y0 + r;
    float4 u = *(const float4*)&R[r][lane * 8];
    float4 v = *(const float4*)&R[r][lane * 8 + 4];
    float nf[8] = {u.x, u.y, u.z, u.w, v.x, v.y, v.z, v.w};
    float up = __shfl_up(prev[7], 1);
    // decision bits (prev = values[y-1]): bit = (x!=0)&((x==y)|(prev[x]<prev[x-1]))
    unsigned byte;
    {
      unsigned bit = (prev[0] < up) ? 1u : 0u;
      if (MASKED && xbase == y) bit = 1u;
      if (lane == 0) bit = 0u;
      byte = bit;
    }
    #pragma unroll
    for (int j = 1; j < 8; ++j) {
      unsigned bit = (prev[j] < prev[j - 1]) ? 1u : 0u;
      if (MASKED && (xbase + j) == y) bit = 1u;
      byte |= bit << j;
    }
    // value update
    float vleft0;
    if (MASKED) vleft0 = (lane == 0) ? ((y == 0) ? 0.0f : NEGINF) : up;
    else        vleft0 = (lane == 0) ? NEGINF : up;
    float nv[8];
    {
      float vc = (MASKED && xbase == y) ? NEGINF : prev[0];
      nv[0] = fmaxf(vc, vleft0) + nf[0];
    }
    #pragma unroll
    for (int j = 1; j < 8; ++j) {
      float vc = (MASKED && (xbase + j) == y) ? NEGINF : prev[j];
      nv[j] = fmaxf(vc, prev[j - 1]) + nf[j];
    }
    #pragma unroll
    for (int j = 0; j < 8; ++j) prev[j] = nv[j];
    packed |= byte << (r * 8);
  }
  bits[y0 >> 2][lane] = packed;
}

__global__ __launch_bounds__(64, 1)
void k_dp(const float* __restrict__ neg, float* __restrict__ dur,
          int* __restrict__ idx_out, const float* __restrict__ x_mask) {
  __shared__ unsigned bits[TFEAT / 4][64];       // 131072 B
  __shared__ float ring[4][CHUNK][TTXT];         //  32768 B (total 160 KiB)
  int b = blockIdx.x;
  int lane = threadIdx.x;
  const float* nb = neg + (size_t)b * TFEAT * TTXT;
  int xbase = lane * 8;

  float prev[8];
  #pragma unroll
  for (int j = 0; j < 8; ++j) prev[j] = NEGINF;

  // stage chunk c (rows 4c..4c+3) into ring[c&3]: 8 x 1KB global_load_lds
  auto stage = [&](int c) {
    int m = c & 3;
    const float* src = nb + (size_t)c * CHUNK * TTXT + lane * 4;
    #pragma unroll
    for (int r = 0; r < CHUNK; ++r) {
      gload_lds16(src + (size_t)r * TTXT,       &ring[m][r][0]);
      gload_lds16(src + (size_t)r * TTXT + 256, &ring[m][r][256]);
    }
  };

  stage(0);
  stage(1);
  stage(2);                                      // 24 outstanding
  for (int c = 0; c < NCH; ++c) {
    if (c + 3 < NCH)       { stage(c + 3); VMCNT(24); }  // c landed; 3 in flight
    else if (c + 3 == NCH)   VMCNT(16);
    else if (c + 2 == NCH)   VMCNT(8);
    else                     VMCNT(0);
    const float (*R)[TTXT] = ring[c & 3];
    if (c < TTXT / CHUNK) dp_rows4<true >(prev, R, c * CHUNK, xbase, lane, bits);
    else                  dp_rows4<false>(prev, R, c * CHUNK, xbase, lane, bits);
  }
  __syncthreads();

  // ---- windowed backtrack: per yq (4 rows), hold words (xq0, xq0-1) in regs,
  // speculatively prefetch 3 words of the next yq (idx moves <= 4 per window).
  const float* xm = x_mask + (size_t)b * TTXT;
  int idx = TTXT - 1, cnt = 0;
  int xq0 = (TTXT - 1) >> 3;
  unsigned c0 = bits[TFEAT / 4 - 1][xq0];
  unsigned c1 = bits[TFEAT / 4 - 1][xq0 - 1];
  for (int yq = TFEAT / 4 - 1; yq >= 0; --yq) {
    unsigned n0 = 0, n1 = 0, n2 = 0;
    if (yq > 0) {
      int i1 = xq0 - 1 > 0 ? xq0 - 1 : 0;
      int i2 = xq0 - 2 > 0 ? xq0 - 2 : 0;
      n0 = bits[yq - 1][xq0];
      n1 = bits[yq - 1][i1];
      n2 = bits[yq - 1][i2];
    }
    #pragma unroll
    for (int r = 3; r >= 0; --r) {
      int y = yq * 4 + r;
      if (lane == 0) idx_out[b * TFEAT + y] = idx;
      cnt++;
      unsigned w = ((idx >> 3) == xq0) ? c0 : c1;
      unsigned bit = (w >> (r * 8 + (idx & 7))) & 1u;
      if (bit) {
        if (lane == 0) dur[b * TTXT + idx] = (float)cnt * xm[idx];
        cnt = 0;
        idx--;
      }
    }
    int nxq = idx >> 3;
    c0 = (nxq == xq0) ? n0 : n1;
    c1 = (nxq == xq0) ? n1 : n2;
    xq0 = nxq;
  }
  if (lane == 0) dur[b * TTXT] = (float)cnt * xm[0];   // idx == 0 tail run
}

// ---------------------------------------------------------------------------
// Kernel D: attn[b,y,x] = (x == idx[y]) * x_mask[b,x] * y_mask[b,y]
// ---------------------------------------------------------------------------
__global__ void k_attn(const int* __restrict__ idx_arr,
                       const float* __restrict__ x_mask,
                       const float* __restrict__ y_mask,
                       float* __restrict__ attn) {
  size_t gid = (size_t)blockIdx.x * 256 + threadIdx.x;
  size_t e = gid << 2;               // 4 floats per thread
  int b = (int)(e >> 20);            // TFEAT*TTXT = 2^20
  int rem = (int)(e & 1048575u);
  int y = rem >> 9;
  int x0 = rem & 511;
  int idx = idx_arr[b * TFEAT + y];
  float4 v = {0.f, 0.f, 0.f, 0.f};
  int d = idx - x0;
  if (d >= 0 && d < 4) {
    ((float*)&v)[d] = x_mask[b * TTXT + idx] * y_mask[b * TFEAT + y];
  }
  *(float4*)(attn + e) = v;
}

// ---------------------------------------------------------------------------
extern "C" void kernel_launch(void* const* d_in, const int* in_sizes, int n_in,
                              void* d_out, int out_size, void* d_ws, size_t ws_size,
                              hipStream_t stream) {
  const float* z_p    = (const float*)d_in[0];
  const float* m_p    = (const float*)d_in[1];
  const float* logs_p = (const float*)d_in[2];
  const float* x_mask = (const float*)d_in[3];
  const float* y_mask = (const float*)d_in[4];

  float* out  = (float*)d_out;
  float* attn = out;
  float* dur  = out + DUR_OFF;
  float* neg  = out + NEG_OFF;

  // W1/W2 scratch lives in the attn region (fully rewritten by k_attn later)
  float* w1s = attn;
  float* w2s = attn + (size_t)BATCH * CH * TTXT;      // 3,145,728 floats each

  // workspace: cadd (64 KiB) + idx array (256 KiB)
  float* cadd = (float*)d_ws;
  int*   idxa = (int*)((char*)d_ws + 65536);

  k_prep<<<(BATCH * CH * TTXT) / 256, 256, 0, stream>>>(m_p, logs_p, w1s, w2s);
  k_cadd<<<(BATCH * TTXT) / 256, 256, 0, stream>>>(m_p, logs_p, cadd);
  k_gemm<<<BATCH * (TFEAT / BM) * (TTXT / BN), 512, 0, stream>>>(z_p, w1s, w2s, cadd, neg);
  k_dp<<<BATCH, 64, 0, stream>>>(neg, dur, idxa, x_mask);
  k_attn<<<(int)(ATTN_ELEMS / 4 / 256), 256, 0, stream>>>(idxa, x_mask, y_mask, attn);
}

// Round 7
// 963.800 us; speedup vs baseline: 6.3393x; 1.0361x over previous
//
#include <hip/hip_runtime.h>
#include <math.h>

// Problem constants (fixed by the reference setup_inputs)
#define BATCH 32
#define CH    192
#define TFEAT 2048
#define TTXT  512
#define NEGINF (-1e9f)

#define ATTN_ELEMS ((size_t)BATCH * TFEAT * TTXT)   // 33,554,432
#define DUR_OFF    ATTN_ELEMS
#define NEG_OFF    (ATTN_ELEMS + (size_t)BATCH * TTXT)

__device__ __forceinline__ void gload_lds16(const float* g, float* l) {
  __builtin_amdgcn_global_load_lds(
      (const __attribute__((address_space(1))) void*)g,
      (__attribute__((address_space(3))) void*)l, 16, 0, 0);
}

// ---------------------------------------------------------------------------
// Kernel P: W1[b,c,s] = m*exp(-2*logs), W2[b,c,s] = -0.5*exp(-2*logs)
// Written into the attn region of d_out (fully rewritten later by k_attn).
// ---------------------------------------------------------------------------
__global__ void k_prep(const float* __restrict__ m_p,
                       const float* __restrict__ logs_p,
                       float* __restrict__ w1, float* __restrict__ w2) {
  int gid = blockIdx.x * 256 + threadIdx.x;    // 0 .. 3,145,727
  float m = m_p[gid];
  float l = logs_p[gid];
  float r = __expf(-2.0f * l);
  w1[gid] = m * r;
  w2[gid] = -0.5f * r;
}

// ---------------------------------------------------------------------------
// Kernel A: cadd[b][s] = sum_c(-0.5*log(2pi) - logs) + sum_c(-0.5*m^2*r)
// ---------------------------------------------------------------------------
__global__ void k_cadd(const float* __restrict__ m_p,
                       const float* __restrict__ logs_p,
                       float* __restrict__ cadd) {
  int gid = blockIdx.x * 256 + threadIdx.x;        // 0 .. 16383
  int b = gid >> 9, s = gid & (TTXT - 1);
  const float* mp = m_p    + (size_t)b * CH * TTXT + s;
  const float* lp = logs_p + (size_t)b * CH * TTXT + s;
  float acc = -0.5f * 1.8378770664093453f * (float)CH;   // -C/2 * log(2*pi)
  #pragma unroll 4
  for (int c = 0; c < CH; ++c) {
    float l = lp[(size_t)c * TTXT];
    float m = mp[(size_t)c * TTXT];
    float r = __expf(-2.0f * l);
    acc -= l + 0.5f * m * m * r;
  }
  cadd[gid] = acc;
}

// ---------------------------------------------------------------------------
// Kernel B: neg[b,t,s] = sum_c z*(W1 + z*W2) + cadd[b,s]
// fp32 vector GEMM, 512 threads, acc[8][4]. Live set designed for the 64-VGPR
// allocation hipcc insists on (R4/R5 spill history in journal). R6: spill
// traffic gone, ~300us. UNCHANGED this round.
// ---------------------------------------------------------------------------
#define BM 128
#define BN 128
#define BK 16

__global__ __launch_bounds__(512)
void k_gemm(const float* __restrict__ z_p,
            const float* __restrict__ w1g, const float* __restrict__ w2g,
            const float* __restrict__ cadd, float* __restrict__ neg) {
  __shared__ float Az[BK][BM];
  __shared__ float B1[BK][BN];
  __shared__ float B2[BK][BN];

  // chunked XCD swizzle (2048 blocks, 8 XCDs, 256 per chunk; bijective)
  int blk = (blockIdx.x & 7) * 256 + (blockIdx.x >> 3);
  int sb = blk & 3;            // TTXT/BN = 4
  int tb = (blk >> 2) & 15;    // TFEAT/BM = 16
  int b  = blk >> 6;
  int tid = threadIdx.x;
  int tx = tid & 31;           // col group: 4 cols at tx*4
  int ty = tid >> 5;           // row group: 8 rows at ty*8  (0..15)
  int wid  = tid >> 6;         // wave 0..7
  int lane = tid & 63;
  int lr = lane >> 5;          // row-within-pair
  int lc = (lane & 31) * 4;    // col (float4 granularity)

  const float* zb  = z_p + (size_t)b * CH * TFEAT + (size_t)tb * BM;
  const float* w1b = w1g + (size_t)b * CH * TTXT  + (size_t)sb * BN;
  const float* w2b = w2g + (size_t)b * CH * TTXT  + (size_t)sb * BN;

  float acc[8][4];
  #pragma unroll
  for (int i = 0; i < 8; ++i)
    #pragma unroll
    for (int j = 0; j < 4; ++j) acc[i][j] = 0.0f;

  for (int ko = 0; ko < CH / BK; ++ko) {
    int k0 = ko * BK;
    // stage 3 tiles: wave wid covers rows {2*wid, 2*wid+1} of each tile
    int kr = k0 + 2 * wid + lr;          // per-lane global k-row
    int kd = 2 * wid;                    // wave-uniform LDS row base
    gload_lds16(zb  + (size_t)kr * TFEAT + lc, &Az[kd][0]);
    gload_lds16(w1b + (size_t)kr * TTXT  + lc, &B1[kd][0]);
    gload_lds16(w2b + (size_t)kr * TTXT  + lc, &B2[kd][0]);
    __syncthreads();                     // drains vmcnt (loads landed)

    #pragma unroll
    for (int kk = 0; kk < BK; ++kk) {
      float4 a0 = *(const float4*)&Az[kk][ty * 8];
      float4 a1 = *(const float4*)&Az[kk][ty * 8 + 4];
      float4 p  = *(const float4*)&B1[kk][tx * 4];
      float4 q  = *(const float4*)&B2[kk][tx * 4];
      float a[8]   = {a0.x, a0.y, a0.z, a0.w, a1.x, a1.y, a1.z, a1.w};
      float w1v[4] = {p.x, p.y, p.z, p.w};
      float w2v[4] = {q.x, q.y, q.z, q.w};
      #pragma unroll
      for (int i = 0; i < 8; ++i)
        #pragma unroll
        for (int j = 0; j < 4; ++j)
          acc[i][j] = fmaf(a[i], fmaf(a[i], w2v[j], w1v[j]), acc[i][j]);
      __builtin_amdgcn_sched_barrier(0); // keep live set <= 64 VGPRs
    }
    __syncthreads();                     // tile consumed before restage
  }

  // epilogue: + cadd, store. rows tb*128 + ty*8 + i; cols sb*128 + tx*4
  float4 cb4 = *(const float4*)(cadd + b * TTXT + sb * BN + tx * 4);
  float c0[4] = {cb4.x, cb4.y, cb4.z, cb4.w};
  float* ob = neg + (size_t)b * TFEAT * TTXT + (size_t)(tb * BM + ty * 8) * TTXT + sb * BN;
  #pragma unroll
  for (int i = 0; i < 8; ++i) {
    float4 o = {acc[i][0] + c0[0], acc[i][1] + c0[1], acc[i][2] + c0[2], acc[i][3] + c0[3]};
    *(float4*)(ob + (size_t)i * TTXT + tx * 4) = o;
  }
}

// ---------------------------------------------------------------------------
// Kernel C: forward DP, latency-trimmed (R7 rewrite):
//  - all 8 ds_read_b128 of a 4-row chunk batched up front (one lgkm drain
//    per chunk, not per row)
//  - raw ds_bpermute with precomputed (lane-1)*4 addr replaces __shfl_up;
//    issued first, consumed last in each row (latency hidden under j=1..7)
//  - x==y force is compile-time per row: (y&7) = JBASE + r, so only one j
//    slot carries the 2-op select (was 16 ops/row)
// One wave per batch element, x = 8*lane + j. Ring-4 LDS staging, 3 ahead.
// ---------------------------------------------------------------------------
#define CHUNK 4                       // rows per staged chunk
#define NCH   (TFEAT / CHUNK)         // 512 chunks

#define VMCNT(n) asm volatile("s_waitcnt vmcnt(" #n ")" ::: "memory")

template<bool MASKED, int JBASE>   // rows y0..y0+3 have (y&7) == JBASE + r
__device__ __forceinline__ void dp_chunk4(float (&prev)[8], const float (*R)[TTXT],
                                          int y0, int lane, int bpaddr,
                                          unsigned (*bits)[64]) {
  // 1) batch-load the whole chunk's nf (8 x ds_read_b128, pipelined)
  float nf[4][8];
  #pragma unroll
  for (int r = 0; r < 4; ++r) {
    float4 u = *(const float4*)&R[r][lane * 8];
    float4 v = *(const float4*)&R[r][lane * 8 + 4];
    nf[r][0] = u.x; nf[r][1] = u.y; nf[r][2] = u.z; nf[r][3] = u.w;
    nf[r][4] = v.x; nf[r][5] = v.y; nf[r][6] = v.z; nf[r][7] = v.w;
  }
  unsigned packed = 0;
  #pragma unroll
  for (int r = 0; r < 4; ++r) {
    const int y = y0 + r;
    const int JF = JBASE + r;            // the j that can satisfy x==y
    // issue neighbor fetch first; consume last
    float up = __int_as_float(
        __builtin_amdgcn_ds_bpermute(bpaddr, __float_as_int(prev[7])));
    bool force = MASKED && (lane == (y >> 3));   // x==y occurs at j==JF
    unsigned byte = 0;
    float nv[8];
    #pragma unroll
    for (int j = 1; j < 8; ++j) {        // independent of `up`
      bool gt = prev[j] < prev[j - 1];
      bool bit = (MASKED && j == JF) ? (force || gt) : gt;
      byte |= ((unsigned)bit) << j;
      float vc = (MASKED && j == JF) ? (force ? NEGINF : prev[j]) : prev[j];
      nv[j] = fmaxf(vc, prev[j - 1]) + nf[r][j];
    }
    {                                    // j = 0 (uses `up`)
      bool gt = prev[0] < up;
      bool bit0 = (MASKED && 0 == JF) ? (force || gt) : gt;
      if (lane == 0) bit0 = false;       // x == 0
      byte |= (unsigned)bit0;
      float vleft0 = (lane == 0) ? ((MASKED && y == 0) ? 0.0f : NEGINF) : up;
      float vc = (MASKED && 0 == JF) ? (force ? NEGINF : prev[0]) : prev[0];
      nv[0] = fmaxf(vc, vleft0) + nf[r][0];
    }
    #pragma unroll
    for (int j = 0; j < 8; ++j) prev[j] = nv[j];
    packed |= byte << (r * 8);
  }
  bits[y0 >> 2][lane] = packed;
}

__global__ __launch_bounds__(64, 1)
void k_dp(const float* __restrict__ neg, float* __restrict__ dur,
          int* __restrict__ idx_out, const float* __restrict__ x_mask) {
  __shared__ unsigned bits[TFEAT / 4][64];       // 131072 B
  __shared__ float ring[4][CHUNK][TTXT];         //  32768 B (total 160 KiB)
  int b = blockIdx.x;
  int lane = threadIdx.x;
  const float* nb = neg + (size_t)b * TFEAT * TTXT;
  int bpaddr = (lane - 1) * 4;                   // ds_bpermute byte addr (lane-1)

  float prev[8];
  #pragma unroll
  for (int j = 0; j < 8; ++j) prev[j] = NEGINF;

  // stage chunk c (rows 4c..4c+3) into ring[c&3]: 8 x 1KB global_load_lds
  auto stage = [&](int c) {
    int m = c & 3;
    const float* src = nb + (size_t)c * CHUNK * TTXT + lane * 4;
    #pragma unroll
    for (int r = 0; r < CHUNK; ++r) {
      gload_lds16(src + (size_t)r * TTXT,       &ring[m][r][0]);
      gload_lds16(src + (size_t)r * TTXT + 256, &ring[m][r][256]);
    }
  };
  auto advance = [&](int c) {            // ensure chunk c landed; keep 3 in flight
    if (c + 3 < NCH)       { stage(c + 3); VMCNT(24); }
    else if (c + 3 == NCH)   VMCNT(16);
    else if (c + 2 == NCH)   VMCNT(8);
    else                     VMCNT(0);
  };

  stage(0);
  stage(1);
  stage(2);                                      // 24 outstanding
  // masked region: chunks 0..127 (y < 512); pair-step fixes (y&7) parity
  for (int c = 0; c < TTXT / CHUNK; c += 2) {
    advance(c);
    dp_chunk4<true, 0>(prev, ring[c & 3], c * CHUNK, lane, bpaddr, bits);
    advance(c + 1);
    dp_chunk4<true, 4>(prev, ring[(c + 1) & 3], (c + 1) * CHUNK, lane, bpaddr, bits);
  }
  // light region: chunks 128..511 (y >= 512, no x==y possible)
  for (int c = TTXT / CHUNK; c < NCH; c += 2) {
    advance(c);
    dp_chunk4<false, 0>(prev, ring[c & 3], c * CHUNK, lane, bpaddr, bits);
    advance(c + 1);
    dp_chunk4<false, 4>(prev, ring[(c + 1) & 3], (c + 1) * CHUNK, lane, bpaddr, bits);
  }
  __syncthreads();

  // ---- windowed backtrack: per yq (4 rows), hold words (xq0, xq0-1) in regs,
  // speculatively prefetch 3 words of the next yq (idx moves <= 4 per window).
  const float* xm = x_mask + (size_t)b * TTXT;
  int idx = TTXT - 1, cnt = 0;
  int xq0 = (TTXT - 1) >> 3;
  unsigned c0 = bits[TFEAT / 4 - 1][xq0];
  unsigned c1 = bits[TFEAT / 4 - 1][xq0 - 1];
  for (int yq = TFEAT / 4 - 1; yq >= 0; --yq) {
    unsigned n0 = 0, n1 = 0, n2 = 0;
    if (yq > 0) {
      int i1 = xq0 - 1 > 0 ? xq0 - 1 : 0;
      int i2 = xq0 - 2 > 0 ? xq0 - 2 : 0;
      n0 = bits[yq - 1][xq0];
      n1 = bits[yq - 1][i1];
      n2 = bits[yq - 1][i2];
    }
    #pragma unroll
    for (int r = 3; r >= 0; --r) {
      int y = yq * 4 + r;
      if (lane == 0) idx_out[b * TFEAT + y] = idx;
      cnt++;
      unsigned w = ((idx >> 3) == xq0) ? c0 : c1;
      unsigned bit = (w >> (r * 8 + (idx & 7))) & 1u;
      if (bit) {
        if (lane == 0) dur[b * TTXT + idx] = (float)cnt * xm[idx];
        cnt = 0;
        idx--;
      }
    }
    int nxq = idx >> 3;
    c0 = (nxq == xq0) ? n0 : n1;
    c1 = (nxq == xq0) ? n1 : n2;
    xq0 = nxq;
  }
  if (lane == 0) dur[b * TTXT] = (float)cnt * xm[0];   // idx == 0 tail run
}

// ---------------------------------------------------------------------------
// Kernel D: attn[b,y,x] = (x == idx[y]) * x_mask[b,x] * y_mask[b,y]
// ---------------------------------------------------------------------------
__global__ void k_attn(const int* __restrict__ idx_arr,
                       const float* __restrict__ x_mask,
                       const float* __restrict__ y_mask,
                       float* __restrict__ attn) {
  size_t gid = (size_t)blockIdx.x * 256 + threadIdx.x;
  size_t e = gid << 2;               // 4 floats per thread
  int b = (int)(e >> 20);            // TFEAT*TTXT = 2^20
  int rem = (int)(e & 1048575u);
  int y = rem >> 9;
  int x0 = rem & 511;
  int idx = idx_arr[b * TFEAT + y];
  float4 v = {0.f, 0.f, 0.f, 0.f};
  int d = idx - x0;
  if (d >= 0 && d < 4) {
    ((float*)&v)[d] = x_mask[b * TTXT + idx] * y_mask[b * TFEAT + y];
  }
  *(float4*)(attn + e) = v;
}

// ---------------------------------------------------------------------------
extern "C" void kernel_launch(void* const* d_in, const int* in_sizes, int n_in,
                              void* d_out, int out_size, void* d_ws, size_t ws_size,
                              hipStream_t stream) {
  const float* z_p    = (const float*)d_in[0];
  const float* m_p    = (const float*)d_in[1];
  const float* logs_p = (const float*)d_in[2];
  const float* x_mask = (const float*)d_in[3];
  const float* y_mask = (const float*)d_in[4];

  float* out  = (float*)d_out;
  float* attn = out;
  float* dur  = out + DUR_OFF;
  float* neg  = out + NEG_OFF;

  // W1/W2 scratch lives in the attn region (fully rewritten by k_attn later)
  float* w1s = attn;
  float* w2s = attn + (size_t)BATCH * CH * TTXT;      // 3,145,728 floats each

  // workspace: cadd (64 KiB) + idx array (256 KiB)
  float* cadd = (float*)d_ws;
  int*   idxa = (int*)((char*)d_ws + 65536);

  k_prep<<<(BATCH * CH * TTXT) / 256, 256, 0, stream>>>(m_p, logs_p, w1s, w2s);
  k_cadd<<<(BATCH * TTXT) / 256, 256, 0, stream>>>(m_p, logs_p, cadd);
  k_gemm<<<BATCH * (TFEAT / BM) * (TTXT / BN), 512, 0, stream>>>(z_p, w1s, w2s, cadd, neg);
  k_dp<<<BATCH, 64, 0, stream>>>(neg, dur, idxa, x_mask);
  k_attn<<<(int)(ATTN_ELEMS / 4 / 256), 256, 0, stream>>>(idxa, x_mask, y_mask, attn);
}